// Round 1
// baseline (1939.789 us; speedup 1.0000x reference)
//
#include <hip/hip_runtime.h>

#define Bsz 65536
#define Rn 64
#define Hn 10
#define Fn 5

__device__ __forceinline__ float fsigmoid(float x) {
    // 1/(1+e^-x) via fast exp + v_rcp_f32
    return __builtin_amdgcn_rcpf(1.0f + __expf(-x));
}
__device__ __forceinline__ float ftanh(float x) {
    // tanh(x) = 1 - 2/(exp(2x)+1)
    return 1.0f - 2.0f * __builtin_amdgcn_rcpf(__expf(2.0f * x) + 1.0f);
}

// One thread per batch element. Weights in LDS (wave-uniform broadcast reads,
// rows padded to 12 floats so 16B-aligned -> ds_read_b128 vectorization).
// Entire reference fused: LSTM recurrence + r-gate + final FC folded into a
// running scalar accumulator (the [B, R*H] intermediate never materializes).
__global__ __launch_bounds__(256, 1) void seqreader_kernel(
    const float* __restrict__ r_emb,
    const float* __restrict__ feature,
    const float* __restrict__ h0,
    const float* __restrict__ c0,
    const float* __restrict__ W_ih,
    const float* __restrict__ W_hh,
    const float* __restrict__ b_ih,
    const float* __restrict__ b_hh,
    const float* __restrict__ Wr,
    const float* __restrict__ br,
    const float* __restrict__ Wh,
    const float* __restrict__ bh,
    const float* __restrict__ Wfc,
    const float* __restrict__ bfc,
    float* __restrict__ out)
{
    // padded row stride 12 -> each row starts 48B-aligned (16B-aligned groups)
    __shared__ __align__(16) float sWih[40 * 12];
    __shared__ __align__(16) float sWhh[40 * 12];
    __shared__ __align__(16) float sWr[10 * 12];
    __shared__ __align__(16) float sWhn[10 * 12];
    __shared__ float sBg[40];    // b_ih + b_hh
    __shared__ float sBr[10];    // br + bh
    __shared__ float sWfc[646];  // Wfc (645) + bfc at [645]

    const int tid = threadIdx.x;

    for (int i = tid; i < 40 * 10; i += 256) {
        int r = i / 10, k = i - r * 10;
        sWih[r * 12 + k] = W_ih[i];
        sWhh[r * 12 + k] = W_hh[i];
    }
    for (int i = tid; i < 10 * 10; i += 256) {
        int r = i / 10, k = i - r * 10;
        sWr[r * 12 + k]  = Wr[i];
        sWhn[r * 12 + k] = Wh[i];
    }
    if (tid < 40) sBg[tid] = b_ih[tid] + b_hh[tid];
    if (tid < 10) sBr[tid] = br[tid] + bh[tid];
    for (int i = tid; i < 645; i += 256) sWfc[i] = Wfc[i];
    if (tid == 0) sWfc[645] = bfc[0];
    __syncthreads();

    const int b = blockIdx.x * 256 + tid;
    const float* __restrict__ xb = r_emb + (size_t)b * (Rn * Hn);

    float h[Hn], c[Hn];
#pragma unroll
    for (int j = 0; j < Hn; ++j) {
        h[j] = h0[b * Hn + j];
        c[j] = c0[b * Hn + j];
    }

    float acc = sWfc[645];
#pragma unroll
    for (int k = 0; k < Fn; ++k) acc = fmaf(feature[b * Fn + k], sWfc[Rn * Hn + k], acc);

    float x[Hn];
#pragma unroll
    for (int j = 0; j < Hn; ++j) x[j] = xb[j];

#pragma unroll 1
    for (int t = 0; t < Rn; ++t) {
        // prefetch next step's x (issues early; compute below hides latency)
        float xn[Hn];
        const int tn = (t + 1 < Rn) ? (t + 1) : t;
#pragma unroll
        for (int j = 0; j < Hn; ++j) xn[j] = xb[tn * Hn + j];

        float hn[Hn];
#pragma unroll
        for (int r = 0; r < Hn; ++r) {
            // gate rows: i@r, f@10+r, g@20+r, o@30+r  (4 independent FMA chains)
            float si = sBg[r], sf = sBg[10 + r], sg = sBg[20 + r], so = sBg[30 + r];
#pragma unroll
            for (int k = 0; k < Hn; ++k) {
                const float xk = x[k], hk = h[k];
                si = fmaf(sWih[r * 12 + k], xk, si);
                si = fmaf(sWhh[r * 12 + k], hk, si);
                sf = fmaf(sWih[(10 + r) * 12 + k], xk, sf);
                sf = fmaf(sWhh[(10 + r) * 12 + k], hk, sf);
                sg = fmaf(sWih[(20 + r) * 12 + k], xk, sg);
                sg = fmaf(sWhh[(20 + r) * 12 + k], hk, sg);
                so = fmaf(sWih[(30 + r) * 12 + k], xk, so);
                so = fmaf(sWhh[(30 + r) * 12 + k], hk, so);
            }
            const float cn = fsigmoid(sf) * c[r] + fsigmoid(si) * ftanh(sg);
            c[r] = cn;
            hn[r] = fsigmoid(so) * ftanh(cn);
        }
        // r-gate + fused FC accumulation
#pragma unroll
        for (int r = 0; r < Hn; ++r) {
            float s = sBr[r];
#pragma unroll
            for (int k = 0; k < Hn; ++k) {
                s = fmaf(sWr[r * 12 + k], x[k], s);
                s = fmaf(sWhn[r * 12 + k], hn[k], s);
            }
            acc = fmaf(hn[r] * fsigmoid(s), sWfc[t * Hn + r], acc);
        }
#pragma unroll
        for (int j = 0; j < Hn; ++j) { h[j] = hn[j]; x[j] = xn[j]; }
    }

    out[b] = acc;
}

extern "C" void kernel_launch(void* const* d_in, const int* in_sizes, int n_in,
                              void* d_out, int out_size, void* d_ws, size_t ws_size,
                              hipStream_t stream) {
    const float* r_emb   = (const float*)d_in[0];
    const float* feature = (const float*)d_in[1];
    const float* h0      = (const float*)d_in[2];
    const float* c0      = (const float*)d_in[3];
    const float* W_ih    = (const float*)d_in[4];
    const float* W_hh    = (const float*)d_in[5];
    const float* b_ih    = (const float*)d_in[6];
    const float* b_hh    = (const float*)d_in[7];
    const float* Wr      = (const float*)d_in[8];
    const float* br      = (const float*)d_in[9];
    const float* Wh      = (const float*)d_in[10];
    const float* bh      = (const float*)d_in[11];
    const float* Wfc     = (const float*)d_in[12];
    const float* bfc     = (const float*)d_in[13];
    float* out = (float*)d_out;

    dim3 grid(Bsz / 256), block(256);
    hipLaunchKernelGGL(seqreader_kernel, grid, block, 0, stream,
                       r_emb, feature, h0, c0, W_ih, W_hh, b_ih, b_hh,
                       Wr, br, Wh, bh, Wfc, bfc, out);
}

// Round 2
// 385.682 us; speedup vs baseline: 5.0295x; 5.0295x over previous
//
#include <hip/hip_runtime.h>

#define Bsz 65536
#define Rn 64
#define Hn 10
#define Fn 5
#define TS 4
#define NT (Rn / TS)
#define XROW 41  // padded dwords per batch row in x-tile (40 used; odd stride -> bank spread)

__device__ __forceinline__ float fsigmoid(float x) {
    return __builtin_amdgcn_rcpf(1.0f + __expf(-x));
}
__device__ __forceinline__ float ftanh(float x) {
    return 1.0f - 2.0f * __builtin_amdgcn_rcpf(__expf(2.0f * x) + 1.0f);
}

// One thread per batch element; 256 batches per block.
// r_emb staged through double-buffered LDS tiles with coalesced global loads
// (the round-1 kernel's 2560B-lane-stride direct loads caused a 36x HBM over-fetch).
__global__ __launch_bounds__(256, 1) void seqreader_kernel(
    const float* __restrict__ r_emb,
    const float* __restrict__ feature,
    const float* __restrict__ h0,
    const float* __restrict__ c0,
    const float* __restrict__ W_ih,
    const float* __restrict__ W_hh,
    const float* __restrict__ b_ih,
    const float* __restrict__ b_hh,
    const float* __restrict__ Wr,
    const float* __restrict__ br,
    const float* __restrict__ Wh,
    const float* __restrict__ bh,
    const float* __restrict__ Wfc,
    const float* __restrict__ bfc,
    float* __restrict__ out)
{
    // weights, rows padded to 12 floats (16B-aligned groups -> ds_read_b128)
    __shared__ __align__(16) float sWih[40 * 12];
    __shared__ __align__(16) float sWhh[40 * 12];
    __shared__ __align__(16) float sWr[10 * 12];
    __shared__ __align__(16) float sWhn[10 * 12];
    __shared__ float sBg[40];    // b_ih + b_hh
    __shared__ float sBr[10];    // br + bh
    __shared__ float sWfc[646];  // Wfc (645) + bfc at [645]
    // double-buffered x tiles: [buf][batch][XROW]
    __shared__ float sX[2][256 * XROW];

    const int tid = threadIdx.x;

    for (int i = tid; i < 40 * 10; i += 256) {
        int r = i / 10, k = i - r * 10;
        sWih[r * 12 + k] = W_ih[i];
        sWhh[r * 12 + k] = W_hh[i];
    }
    for (int i = tid; i < 10 * 10; i += 256) {
        int r = i / 10, k = i - r * 10;
        sWr[r * 12 + k]  = Wr[i];
        sWhn[r * 12 + k] = Wh[i];
    }
    if (tid < 40) sBg[tid] = b_ih[tid] + b_hh[tid];
    if (tid < 10) sBr[tid] = br[tid] + bh[tid];
    for (int i = tid; i < 645; i += 256) sWfc[i] = Wfc[i];
    if (tid == 0) sWfc[645] = bfc[0];

    const int b0 = blockIdx.x * 256;
    const int b  = b0 + tid;

    // per-thread gather map: float4 index q = k*256 + tid -> batch q/10, elem q%10
    unsigned off_g[10];  // byte offset into this block's r_emb slice (tile-relative)
    unsigned off_l[10];  // dword offset into sX buffer
#pragma unroll
    for (int k = 0; k < 10; ++k) {
        int q  = k * 256 + tid;
        int bb = q / 10;
        int e  = q - bb * 10;
        off_g[k] = (unsigned)((bb * (Rn * Hn) + e * 4) * 4);
        off_l[k] = (unsigned)(bb * XROW + e * 4);
    }
    const char* gb = (const char*)(r_emb + (size_t)b0 * (Rn * Hn));

    float h[Hn], c[Hn];
#pragma unroll
    for (int j = 0; j < Hn; ++j) {
        h[j] = h0[b * Hn + j];
        c[j] = c0[b * Hn + j];
    }

    // prologue: stage tile 0 into buffer 0
    {
        float4 st[10];
#pragma unroll
        for (int k = 0; k < 10; ++k)
            st[k] = *(const float4*)(gb + off_g[k]);
#pragma unroll
        for (int k = 0; k < 10; ++k) {
            float* d = &sX[0][off_l[k]];
            d[0] = st[k].x; d[1] = st[k].y; d[2] = st[k].z; d[3] = st[k].w;
        }
    }
    __syncthreads();

    float acc = sWfc[645];
#pragma unroll
    for (int k = 0; k < Fn; ++k) acc = fmaf(feature[b * Fn + k], sWfc[Rn * Hn + k], acc);

#pragma unroll 1
    for (int T = 0; T < NT; ++T) {
        const int cur   = T & 1;
        const bool pref = (T + 1 < NT);
        float4 st[10];
        if (pref) {
#pragma unroll
            for (int k = 0; k < 10; ++k)
                st[k] = *(const float4*)(gb + off_g[k] + (unsigned)(T + 1) * 160u);
        }

#pragma unroll 1
        for (int tt = 0; tt < TS; ++tt) {
            // write next tile into the other buffer mid-way: vmcnt wait lands
            // after ~2 steps of FMA (hides HBM latency), writes overlap rest.
            if (tt == 2 && pref) {
#pragma unroll
                for (int k = 0; k < 10; ++k) {
                    float* d = &sX[cur ^ 1][off_l[k]];
                    d[0] = st[k].x; d[1] = st[k].y; d[2] = st[k].z; d[3] = st[k].w;
                }
            }

            const int t = T * TS + tt;
            const float* xr = &sX[cur][tid * XROW + tt * Hn];
            float x[Hn];
#pragma unroll
            for (int j = 0; j < Hn; ++j) x[j] = xr[j];

            float hn[Hn];
#pragma unroll
            for (int r = 0; r < Hn; ++r) {
                float si = sBg[r], sf = sBg[10 + r], sg = sBg[20 + r], so = sBg[30 + r];
#pragma unroll
                for (int k = 0; k < Hn; ++k) {
                    const float xk = x[k], hk = h[k];
                    si = fmaf(sWih[r * 12 + k], xk, si);
                    si = fmaf(sWhh[r * 12 + k], hk, si);
                    sf = fmaf(sWih[(10 + r) * 12 + k], xk, sf);
                    sf = fmaf(sWhh[(10 + r) * 12 + k], hk, sf);
                    sg = fmaf(sWih[(20 + r) * 12 + k], xk, sg);
                    sg = fmaf(sWhh[(20 + r) * 12 + k], hk, sg);
                    so = fmaf(sWih[(30 + r) * 12 + k], xk, so);
                    so = fmaf(sWhh[(30 + r) * 12 + k], hk, so);
                }
                const float cn = fsigmoid(sf) * c[r] + fsigmoid(si) * ftanh(sg);
                c[r] = cn;
                hn[r] = fsigmoid(so) * ftanh(cn);
            }
#pragma unroll
            for (int r = 0; r < Hn; ++r) {
                float s = sBr[r];
#pragma unroll
                for (int k = 0; k < Hn; ++k) {
                    s = fmaf(sWr[r * 12 + k], x[k], s);
                    s = fmaf(sWhn[r * 12 + k], hn[k], s);
                }
                acc = fmaf(hn[r] * fsigmoid(s), sWfc[t * Hn + r], acc);
            }
#pragma unroll
            for (int j = 0; j < Hn; ++j) h[j] = hn[j];
        }
        __syncthreads();
    }

    out[b] = acc;
}

extern "C" void kernel_launch(void* const* d_in, const int* in_sizes, int n_in,
                              void* d_out, int out_size, void* d_ws, size_t ws_size,
                              hipStream_t stream) {
    const float* r_emb   = (const float*)d_in[0];
    const float* feature = (const float*)d_in[1];
    const float* h0      = (const float*)d_in[2];
    const float* c0      = (const float*)d_in[3];
    const float* W_ih    = (const float*)d_in[4];
    const float* W_hh    = (const float*)d_in[5];
    const float* b_ih    = (const float*)d_in[6];
    const float* b_hh    = (const float*)d_in[7];
    const float* Wr      = (const float*)d_in[8];
    const float* br      = (const float*)d_in[9];
    const float* Wh      = (const float*)d_in[10];
    const float* bh      = (const float*)d_in[11];
    const float* Wfc     = (const float*)d_in[12];
    const float* bfc     = (const float*)d_in[13];
    float* out = (float*)d_out;

    dim3 grid(Bsz / 256), block(256);
    hipLaunchKernelGGL(seqreader_kernel, grid, block, 0, stream,
                       r_emb, feature, h0, c0, W_ih, W_hh, b_ih, b_hh,
                       Wr, br, Wh, bh, Wfc, bfc, out);
}